// Round 18
// baseline (192.724 us; speedup 1.0000x reference)
//
#include <hip/hip_runtime.h>

// SNN forward: [merged preps] -> [GEMM1+scan1 fused, 128x128, LDS-dbuf
// K-loop, 8 waves, BALLOT bit-packed spike output] -> GEMM2 (bitmask-decoded
// A, 64-row, 500 blk) -> scan2 (single-phase LDS, static ring).
// f16 split-2: W = hi + lo, residual ~2^-24 => fp32-grade MFMA results.
// Spikes carried as 1 bit each (4 MB) instead of f16 (64 MB write + 65 MB
// read); gemm2 decodes A-fragments from bits in registers (bit-exact 1.0/0.0).
// Lessons: compile-time ring/dbuf indices (R9); LDS-staged dbuf optimum
// (R10; register-dbuf = VGPR cliff R11/R12); partial-GEMM2 fusion loses (R14);
// g1s1 structurally pinned at ~66us by barrier vmcnt(0) drain (R10-R16).

#define NN 64
#define II 256
#define HH 1024
#define OO 18
#define TT 500

#define D_SR 0.9048374180359595f   // exp(-1/10)
#define C_SR 0.27182818284590454f  // e/10
#define D_RF 0.36787944117144233f  // exp(-1)
#define C_RF 2.718281828459045f    // e
#define THETA 10.0f
#define REFS (-20.0f)

typedef _Float16 f16;
typedef _Float16 f16x8 __attribute__((ext_vector_type(8)));
typedef float f32x4 __attribute__((ext_vector_type(4)));
typedef unsigned long long u64;

__device__ __forceinline__ void gl2lds16(const void* g, void* l) {
    __builtin_amdgcn_global_load_lds(
        (const __attribute__((address_space(1))) void*)g,
        (__attribute__((address_space(3))) void*)l, 16, 0, 0);
}

// ---------------- merged prep: X transpose + W1 hi/lo + W2 hi/lo ------------
__launch_bounds__(256)
__global__ void prep_all(const float* __restrict__ X, const float* __restrict__ W1,
                         const float* __restrict__ W2, f16* __restrict__ Xb,
                         f16* __restrict__ W1h, f16* __restrict__ W1l,
                         f16* __restrict__ W2h, f16* __restrict__ W2l) {
    __shared__ float tile[64][65];
    const int b = blockIdx.x;
    const int tid = threadIdx.x;

    if (b < 2048) {
        const int t0 = (b & 7) * 64, i0 = ((b >> 3) & 3) * 64, n = b >> 5;
        const int tx = tid & 63, q = tid >> 6;
        const float* Xn = X + (size_t)n * II * TT;
#pragma unroll 4
        for (int j = 0; j < 16; ++j) {
            int il = j * 4 + q;
            int t = t0 + tx;
            tile[il][tx] = (t < TT) ? Xn[(size_t)(i0 + il) * TT + t] : 0.f;
        }
        __syncthreads();
#pragma unroll 4
        for (int j = 0; j < 16; ++j) {
            int tl = j * 4 + q;
            int t = t0 + tl;
            if (t < TT)
                Xb[((size_t)n * TT + t) * II + i0 + tx] = (f16)tile[tx][tl];
        }
    } else if (b < 3072) {
        int idx = (b - 2048) * 256 + tid;
        float w = W1[idx];
        f16 h = (f16)w;
        f16 l = (f16)(w - (float)h);
        W1h[idx] = h;
        W1l[idx] = l;
    } else {
        int idx = (b - 3072) * 256 + tid;
        int o = idx >> 10;
        float w = (o < OO) ? W2[idx] : 0.f;
        f16 h = (f16)w;
        f16 l = (f16)(w - (float)h);
        W2h[idx] = h;
        W2l[idx] = l;
    }
}

// ---------------- FUSED layer 1: 128x128 tile, dbuf K-loop, 8 waves ---------
// grid (8, 64), 512 thr. Spike output: __ballot per wave per t -> u64 store
// by lane 0. Sb layout: u64[m = n*TT+t][16], block(ht) owns idx ht*2+{0,1}.
__launch_bounds__(512)
__global__ void gemm1_scan1(const f16* __restrict__ Xb, const f16* __restrict__ Wh,
                            const f16* __restrict__ Wl, u64* __restrict__ Sb) {
    __shared__ __align__(16) char smem[128 * 132 * 4];  // 67,584 B
    float* yb = (float*)smem;

    const int tid = threadIdx.x;
    const int wave = tid >> 6, lane = tid & 63;

    // XCD swizzle: the 8 h-tiles of one n share an XCD
    const int f = blockIdx.y * 8 + blockIdx.x;
    const int x = f & 7, g = f >> 3;
    const int n = x * 8 + (g & 7);
    const int ht = g >> 3;
    const int h0g = ht * 128;

    const int rbl = wave * 16 + (lane >> 2);   // staged row 0..127
    const int koff = (lane & 3) * 8;
    const f16* gBh0 = Wh + (size_t)(h0g + rbl) * II + koff;
    const f16* gBl0 = Wl + (size_t)(h0g + rbl) * II + koff;

    const int wm = wave & 1, wn = wave >> 1;   // 2m x 4n
    const int fr = lane & 15, kq = lane >> 4;

    float p1 = 0.f, a1 = 0.f, p2 = 0.f, a2 = 0.f;  // scan state (tid<128)

    for (int c = 0; c < 4; ++c) {
        const int t0 = c * 128;
        const int TCe = (TT - t0 < 128) ? (TT - t0) : 128;

        int r0 = rbl; if (r0 > TCe - 1) r0 = TCe - 1;
        const f16* gA0 = Xb + ((size_t)n * TT + t0 + r0) * II + koff;

        auto stage = [&](int kk2, int b) {
            f16* As_b = (f16*)(smem + b * 24576);
            f16* Bh_b = As_b + 4096;
            f16* Bl_b = As_b + 8192;
            const int ko = kk2 * 32;
            gl2lds16(gA0 + ko, As_b + wave * 512);
            gl2lds16(gBh0 + ko, Bh_b + wave * 512);
            gl2lds16(gBl0 + ko, Bl_b + wave * 512);
        };

        stage(0, 0);  // previous chunk's post-scan barrier protects yb base

        f32x4 acc[4][2] = {};
        for (int kk = 0; kk < 8; ++kk) {
            __syncthreads();                 // buf[kk&1] DMA drained here
            if (kk < 7) stage(kk + 1, (kk + 1) & 1);

            const f16* As_b = (const f16*)(smem + (kk & 1) * 24576);
            const f16* Bh_b = As_b + 4096;
            const f16* Bl_b = As_b + 8192;

            f16x8 av[4], bhv[2], blv[2];
#pragma unroll
            for (int i = 0; i < 4; ++i)
                av[i] = *(const f16x8*)(As_b + (wm * 64 + i * 16 + fr) * 32 + kq * 8);
#pragma unroll
            for (int j = 0; j < 2; ++j) {
                bhv[j] = *(const f16x8*)(Bh_b + (wn * 32 + j * 16 + fr) * 32 + kq * 8);
                blv[j] = *(const f16x8*)(Bl_b + (wn * 32 + j * 16 + fr) * 32 + kq * 8);
            }
#pragma unroll
            for (int i = 0; i < 4; ++i)
#pragma unroll
                for (int j = 0; j < 2; ++j) {
                    acc[i][j] = __builtin_amdgcn_mfma_f32_16x16x32_f16(av[i], bhv[j], acc[i][j], 0, 0, 0);
                    acc[i][j] = __builtin_amdgcn_mfma_f32_16x16x32_f16(av[i], blv[j], acc[i][j], 0, 0, 0);
                }
        }
        __syncthreads();  // all frag reads done before epilogue overwrites staging

        // epilogue: acc -> yb (t-major, stride 132)
#pragma unroll
        for (int i = 0; i < 4; ++i)
#pragma unroll
            for (int j = 0; j < 2; ++j) {
                int tr = wm * 64 + i * 16 + kq * 4;
                int hc = wn * 32 + j * 16 + fr;
#pragma unroll
                for (int r = 0; r < 4; ++r)
                    yb[(tr + r) * 132 + hc] = acc[i][j][r];
            }
        __syncthreads();

        // sequential scan (waves 0-1); 8-deep ring; spikes -> ballot bits
        if (tid < 128) {
            u64* sq = Sb + ((size_t)(n * TT + t0)) * 16 + ht * 2 + wave;
            float rb_[8];
#pragma unroll
            for (int j = 0; j < 8; ++j) rb_[j] = yb[j * 132 + tid];
            int t = 0;
            for (; t + 8 <= TCe; t += 8) {
#pragma unroll
                for (int j = 0; j < 8; ++j) {
                    float xv = rb_[j];
                    int tn = t + j + 8;
                    rb_[j] = (tn < TCe) ? yb[tn * 132 + tid] : 0.f;
                    a1 = D_SR * (a1 + p1);
                    p1 = D_SR * p1 + xv;
                    float ut = C_SR * a1;
                    a2 = D_RF * (a2 + p2);
                    float u = ut + C_RF * a2;
                    float s = (u >= THETA) ? 1.0f : 0.0f;
                    p2 = D_RF * p2 + REFS * s;
                    u64 bm = __ballot(u >= THETA);
                    if (lane == 0) sq[(size_t)(t + j) * 16] = bm;
                }
            }
            int rem = TCe - t;
#pragma unroll
            for (int j = 0; j < 8; ++j) {
                if (j < rem) {
                    float xv = rb_[j];
                    a1 = D_SR * (a1 + p1);
                    p1 = D_SR * p1 + xv;
                    float ut = C_SR * a1;
                    a2 = D_RF * (a2 + p2);
                    float u = ut + C_RF * a2;
                    float s = (u >= THETA) ? 1.0f : 0.0f;
                    p2 = D_RF * p2 + REFS * s;
                    u64 bm = __ballot(u >= THETA);
                    if (lane == 0) sq[(size_t)(t + j) * 16] = bm;
                }
            }
        }
        __syncthreads();  // yb reads done; next chunk's staging may overwrite
    }
}

// ---------------- GEMM2: bitmask-decoded A, split-f16 B, dbuf ---------------
// grid 500; 256 thr; tile 64 m x 32 o; K=1024, BK=32.
// A: 8 KB bitmask loaded to LDS once (stride 33 u32 vs bank conflicts),
// fragments decoded in registers: bit (kq*8+j) of u32[row][kk] -> 1.0/0.0.
__launch_bounds__(256)
__global__ void gemm2_mfma(const u64* __restrict__ Sb, const f16* __restrict__ W2h,
                           const f16* __restrict__ W2l, float* __restrict__ Y2) {
    __shared__ unsigned int bits[64 * 33];        // 8,448 B
    __shared__ __align__(16) f16 Bh[2][32 * 32];  // 2 x 2 KB
    __shared__ __align__(16) f16 Bl[2][32 * 32];  // 2 x 2 KB

    const int tid = threadIdx.x;
    const int wave = tid >> 6, lane = tid & 63;
    const int m0 = blockIdx.x * 64;
    const int fr = lane & 15, kq = lane >> 4;

    // load bitmask rows m0..m0+63 (128 B each), coalesced
    const unsigned int* g32 = (const unsigned int*)Sb + (size_t)m0 * 32;
    for (int e = tid; e < 2048; e += 256)
        bits[(e >> 5) * 33 + (e & 31)] = g32[e];

    const f16* gB = (wave < 2 ? W2h : W2l) + (size_t)((wave & 1) * 16 + (lane >> 2)) * HH + (lane & 3) * 8;

    auto stageB = [&](int kk2, int b) {
        gl2lds16(gB + kk2 * 32, (wave < 2 ? &Bh[b][0] : &Bl[b][0]) + (wave & 1) * 512);
    };

    stageB(0, 0);

    f32x4 acc[2] = {};
    const int brow = (wave * 16 + fr) * 33;
    const f16 onef = (f16)1.0f, zerof = (f16)0.0f;
    for (int kk = 0; kk < HH / 32; ++kk) {
        __syncthreads();
        if (kk < HH / 32 - 1) stageB(kk + 1, (kk + 1) & 1);
        const int b = kk & 1;

        unsigned int bw = bits[brow + kk];
        f16x8 a;
#pragma unroll
        for (int j = 0; j < 8; ++j)
            a[j] = ((bw >> (kq * 8 + j)) & 1u) ? onef : zerof;

        f16x8 bh[2], bl[2];
#pragma unroll
        for (int j = 0; j < 2; ++j) {
            bh[j] = *(const f16x8*)(&Bh[b][(j * 16 + fr) * 32 + kq * 8]);
            bl[j] = *(const f16x8*)(&Bl[b][(j * 16 + fr) * 32 + kq * 8]);
        }
#pragma unroll
        for (int j = 0; j < 2; ++j) {
            acc[j] = __builtin_amdgcn_mfma_f32_16x16x32_f16(a, bh[j], acc[j], 0, 0, 0);
            acc[j] = __builtin_amdgcn_mfma_f32_16x16x32_f16(a, bl[j], acc[j], 0, 0, 0);
        }
    }

#pragma unroll
    for (int j = 0; j < 2; ++j) {
        int rbase = m0 + wave * 16 + kq * 4;
        int cc = j * 16 + fr;
        float* p = Y2 + (size_t)rbase * 32 + cc;
#pragma unroll
        for (int r = 0; r < 4; ++r)
            p[(size_t)r * 32] = acc[j][r];
    }
}

// ---------------- scan2: single-phase LDS, static-index ring ----------------
__launch_bounds__(256)
__global__ void scan2_k(const float* __restrict__ Y2, float* __restrict__ Out) {
    __shared__ float yc[TT * 32];    // 64,000 B
    __shared__ float sb[OO * TT];    // 36,000 B
    const int n = blockIdx.x, tid = threadIdx.x;

    const float4* src = (const float4*)(Y2 + (size_t)n * TT * 32);
    float4* dst = (float4*)yc;
    for (int i = tid; i < TT * 8; i += 256) dst[i] = src[i];
    __syncthreads();

    if (tid < 32) {
        float p1 = 0.f, a1 = 0.f, p2 = 0.f, a2 = 0.f;
        float rb_[8];
#pragma unroll
        for (int j = 0; j < 8; ++j) rb_[j] = yc[j * 32 + tid];
        int t = 0;
        for (; t + 8 <= TT; t += 8) {
#pragma unroll
            for (int j = 0; j < 8; ++j) {
                float xv = rb_[j];
                int tn = t + j + 8;
                rb_[j] = (tn < TT) ? yc[tn * 32 + tid] : 0.f;
                a1 = D_SR * (a1 + p1);
                p1 = D_SR * p1 + xv;
                float ut = C_SR * a1;
                a2 = D_RF * (a2 + p2);
                float u = ut + C_RF * a2;
                float s = (u >= THETA) ? 1.0f : 0.0f;
                p2 = D_RF * p2 + REFS * s;
                if (tid < OO) sb[tid * TT + t + j] = s;
            }
        }
#pragma unroll
        for (int j = 0; j < 8; ++j) {
            if (t + j < TT) {
                float xv = rb_[j];
                a1 = D_SR * (a1 + p1);
                p1 = D_SR * p1 + xv;
                float ut = C_SR * a1;
                a2 = D_RF * (a2 + p2);
                float u = ut + C_RF * a2;
                float s = (u >= THETA) ? 1.0f : 0.0f;
                p2 = D_RF * p2 + REFS * s;
                if (tid < OO) sb[tid * TT + t + j] = s;
            }
        }
    }
    __syncthreads();

    float* on = Out + (size_t)n * OO * TT;
    for (int e = tid; e < OO * TT; e += 256) on[e] = sb[e];
}

extern "C" void kernel_launch(void* const* d_in, const int* in_sizes, int n_in,
                              void* d_out, int out_size, void* d_ws, size_t ws_size,
                              hipStream_t stream) {
    const float* X  = (const float*)d_in[0];
    const float* W1 = (const float*)d_in[1];
    const float* W2 = (const float*)d_in[2];
    float* out = (float*)d_out;

    const size_t s_sb = (size_t)NN * TT * 16 * 8;   //  4,096,000 (bit-packed s1)
    const size_t s_Xb = (size_t)NN * TT * II * 2;   // 16,384,000
    const size_t s_W  = (size_t)HH * II * 2;        //    524,288 (x2)
    const size_t s_W2 = (size_t)32 * HH * 2;        //     65,536 (x2)
    // + y2 4,096,000 => ~25.8 MB total

    char* w = (char*)d_ws;
    u64*   s1b = (u64*)w;  w += s_sb;
    f16*   Xb  = (f16*)w;  w += s_Xb;
    f16*   W1h = (f16*)w;  w += s_W;
    f16*   W1l = (f16*)w;  w += s_W;
    f16*   W2h = (f16*)w;  w += s_W2;
    f16*   W2l = (f16*)w;  w += s_W2;
    float* y2  = (float*)w;

    prep_all<<<3200, 256, 0, stream>>>(X, W1, W2, Xb, W1h, W1l, W2h, W2l);

    gemm1_scan1<<<dim3(8, NN), 512, 0, stream>>>(Xb, W1h, W1l, s1b);

    gemm2_mfma<<<(NN * TT) / 64, 256, 0, stream>>>(s1b, W2h, W2l, y2);
    scan2_k<<<NN, 256, 0, stream>>>(y2, out);
}